// Round 9
// baseline (310.201 us; speedup 1.0000x reference)
//
#include <hip/hip_runtime.h>
#include <hip/hip_bf16.h>

// MoE forward: T=4096, H=1024, FFN=4096, E=8, top-2, capacity=1024.
// R9: heterogeneous-block overlap. 3 launches + sort:
//   A) fused_pre: router(1024 blk) U conv_w1(8192 blk) U out-init(2048 blk)
//      -- independent blocks, verbatim-verified per-path bodies.
//   B) gemm1(2048 blk, R8-verbatim m97-structure) U conv_w2->w2t(8192 blk,
//      disjoint region at +142.7MiB, ws-guarded; fallback = standalone).
//   C) gemm2: R8 K-loop, K-split 2 -> 1024 blocks = 4 blocks/CU
//      (R8 measured: co-residency is the lever; 512 blk was grid-limited).
// GEMM structure (R8-verified): 128^2 tile, 4 waves, single-buffered 32KiB
// LDS, stage -> vmcnt(0)+barrier -> MFMA -> barrier; XOR granule swizzle;
// expert->XCD bijective block swizzle.
//
// ws layout:
//   [0, 64MiB)    hbuf  bf16 [8][1024][4096]
//   +67108864     te    int[8192]
//   +67141632     ew    float[8192]
//   +67174400     perm  int[8192]
//   +67239936     wt    bf16 64MiB  (w1t [e][f][h]; fallback also w2t)
//   +134348800    xb    bf16 [4096][1024]
//   +142737408    w2t   bf16 64MiB  (fused path; needs ws >= ~200MiB)

#define T_TOK 4096
#define HS 1024
#define FFN 4096
#define NE 8
#define CAP 1024
#define TKS 8192

#define WS_TE   67108864
#define WS_EW   67141632
#define WS_PERM 67174400
#define WS_WT   67239936
#define WS_XB   134348800
#define WS_W2T  142737408
#define WS_W2T_END (WS_W2T + 67108864)

typedef float f4 __attribute__((ext_vector_type(4)));
typedef __bf16 bf16x8 __attribute__((ext_vector_type(8)));
typedef float f32x4 __attribute__((ext_vector_type(4)));

__device__ __forceinline__ void gld_lds16(const void* g, void* l) {
    __builtin_amdgcn_global_load_lds(
        (const __attribute__((address_space(1))) unsigned int*)g,
        (__attribute__((address_space(3))) unsigned int*)l, 16, 0, 0);
}

// ---------------- kernel A: router U conv_w1 U out-init ----------------
// blocks [0,1024): router (4 tokens each)
// blocks [1024,9216): conv_w1 tile (K=HS -> 16 kb, N=FFN -> 64 nb)
// blocks [9216,11264): zero out + bias
__global__ __launch_bounds__(256) void fused_pre_kernel(const float* __restrict__ x,
                                                        const float* __restrict__ rw,
                                                        int* __restrict__ te,
                                                        float* __restrict__ ew,
                                                        __bf16* __restrict__ xb,
                                                        const float* __restrict__ w1,
                                                        __bf16* __restrict__ w1t,
                                                        float* __restrict__ out,
                                                        const float* __restrict__ bias) {
    __shared__ float rwt[NE * HS];   // router: 32KB; conv reuses first 9216B
    const int b = blockIdx.x;
    const int tid = threadIdx.x;

    if (b < 1024) {
        // ---- router (R4/R8-verbatim) ----
        for (int i = tid; i < NE * HS; i += 256) {
            int h = i >> 3, e = i & 7;
            rwt[e * HS + h] = rw[i];
        }
        __syncthreads();
        int wave = tid >> 6, lane = tid & 63;
        int t = b * 4 + wave;
        const float* xr = x + (size_t)t * HS;
        float s[NE];
        float xv[16];
#pragma unroll
        for (int e = 0; e < NE; ++e) s[e] = 0.0f;
#pragma unroll
        for (int j = 0; j < 16; ++j) {
            int h = lane + j * 64;
            xv[j] = xr[h];
#pragma unroll
            for (int e = 0; e < NE; ++e) s[e] += xv[j] * rwt[e * HS + h];
        }
#pragma unroll
        for (int j = 0; j < 16; ++j)
            xb[(size_t)t * HS + lane + j * 64] = (__bf16)xv[j];
#pragma unroll
        for (int e = 0; e < NE; ++e) {
#pragma unroll
            for (int off = 1; off < 64; off <<= 1) s[e] += __shfl_xor(s[e], off, 64);
        }
        float m = s[0];
#pragma unroll
        for (int e = 1; e < NE; ++e) m = fmaxf(m, s[e]);
        float psum = 0.0f;
#pragma unroll
        for (int e = 0; e < NE; ++e) psum += __expf(s[e] - m);
        int e0 = 0; float v0 = s[0];
#pragma unroll
        for (int e = 1; e < NE; ++e) { if (s[e] > v0) { v0 = s[e]; e0 = e; } }
        int e1 = -1; float v1 = -1e30f;
#pragma unroll
        for (int e = 0; e < NE; ++e) { if (e != e0 && s[e] > v1) { v1 = s[e]; e1 = e; } }
        if (lane == 0) {
            float inv = 1.0f / psum;
            te[2 * t]     = e0;
            te[2 * t + 1] = e1;
            ew[2 * t]     = __expf(v0 - m) * inv;
            ew[2 * t + 1] = __expf(v1 - m) * inv;
        }
    } else if (b < 9216) {
        // ---- conv_w1 tile (verbatim conv_wt body, K=HS, N=FFN) ----
        __bf16 (*t)[72] = (__bf16(*)[72])rwt;
        const int cb = b - 1024;
        const int e = cb >> 10, r = cb & 1023;
        const int kb = (r >> 6) * 64, nb = (r & 63) * 64;
        const float* src = w1 + ((size_t)e * HS + kb) * FFN + nb;
        {
            const int kk = tid >> 4, nc = (tid & 15) * 4;
#pragma unroll
            for (int i = 0; i < 4; ++i) {
                int k = kk + 16 * i;
                f4 v = *(const f4*)(src + (size_t)k * FFN + nc);
                t[nc + 0][k] = (__bf16)v[0];
                t[nc + 1][k] = (__bf16)v[1];
                t[nc + 2][k] = (__bf16)v[2];
                t[nc + 3][k] = (__bf16)v[3];
            }
        }
        __syncthreads();
        __bf16* dst = w1t + ((size_t)e * FFN + nb) * HS + kb;
        const int nn = tid >> 3, ch = (tid & 7) * 8;
#pragma unroll
        for (int i = 0; i < 2; ++i) {
            int n = nn + 32 * i;
            bf16x8 v = *(const bf16x8*)(&t[n][ch]);
            *(bf16x8*)(dst + (size_t)n * HS + ch) = v;
        }
    } else {
        // ---- out zero + bias ----
        const int TOT4 = (T_TOK * HS + HS) >> 2;
        const int TH4  = (T_TOK * HS) >> 2;
        const int idx = (b - 9216) * 256 + tid;          // 524288 threads
        for (int i4 = idx; i4 < TOT4; i4 += 2048 * 256) {
            f4 v = (f4)0.0f;
            if (i4 >= TH4) v = *(const f4*)(bias + (((size_t)i4 - TH4) << 2));
            *(f4*)(out + ((size_t)i4 << 2)) = v;
        }
    }
}

// ---------------- stable counting sort by expert (verified) ----------------
__global__ __launch_bounds__(256) void sort_kernel(const int* __restrict__ te,
                                                   int* __restrict__ perm) {
    __shared__ int hist[256 * NE];
    int tid = threadIdx.x;
#pragma unroll
    for (int e = 0; e < NE; ++e) hist[tid * NE + e] = 0;
    for (int i = tid; i < TKS; i += 256) perm[i] = -1;
    __syncthreads();
    for (int j = 0; j < 32; ++j) {
        int p = tid * 32 + j;
        hist[tid * NE + te[p]]++;
    }
    __syncthreads();
    if (tid < NE) {
        int run = 0;   // per-expert restart: within-expert rank
        for (int i = 0; i < 256; ++i) {
            int v = hist[i * NE + tid];
            hist[i * NE + tid] = run;
            run += v;
        }
    }
    __syncthreads();
    for (int j = 0; j < 32; ++j) {
        int p = tid * 32 + j;
        int e = te[p];
        int c = hist[tid * NE + e]++;
        if (c < CAP) perm[e * CAP + c] = p;
    }
}

// ---------------- standalone conv (fallback for w2) ----------------
__global__ __launch_bounds__(256) void conv_wt_kernel(const float* __restrict__ w,
                                                      __bf16* __restrict__ wt,
                                                      int K, int N) {
    __shared__ __bf16 t[64][72];
    const int e = blockIdx.z;
    const int kb = blockIdx.y * 64, nb = blockIdx.x * 64;
    const int tid = threadIdx.x;
    const float* src = w + ((size_t)e * K + kb) * N + nb;
    {
        const int kk = tid >> 4, nc = (tid & 15) * 4;
#pragma unroll
        for (int i = 0; i < 4; ++i) {
            int k = kk + 16 * i;
            f4 v = *(const f4*)(src + (size_t)k * N + nc);
            t[nc + 0][k] = (__bf16)v[0];
            t[nc + 1][k] = (__bf16)v[1];
            t[nc + 2][k] = (__bf16)v[2];
            t[nc + 3][k] = (__bf16)v[3];
        }
    }
    __syncthreads();
    __bf16* dst = wt + ((size_t)e * N + nb) * K + kb;
    const int nn = tid >> 3, ch = (tid & 7) * 8;
#pragma unroll
    for (int i = 0; i < 2; ++i) {
        int n = nn + 32 * i;
        bf16x8 v = *(const bf16x8*)(&t[n][ch]);
        *(bf16x8*)(dst + (size_t)n * K + ch) = v;
    }
}

// ---------------- 128^2 single-buffered GEMM (R8-verified) ----------------

#define STAGE8(koff_) do {                                                  \
    _Pragma("unroll")                                                       \
    for (int j = 0; j < 4; ++j) {                                           \
        gld_lds16(aptr[j] + (koff_), &As[j * 32 + w * 8][0]);               \
        gld_lds16(bptr[j] + (koff_), &Bs[j * 32 + w * 8][0]);               \
    }                                                                       \
} while (0)

#define TILE_BODY() do {                                                    \
    _Pragma("unroll")                                                       \
    for (int kk = 0; kk < 2; ++kk) {                                        \
        const int g = (kk * 4 + (lane >> 4)) ^ (lane & 7);                  \
        bf16x8 af[4], bb[4];                                                \
        _Pragma("unroll")                                                   \
        for (int mi = 0; mi < 4; ++mi)                                      \
            af[mi] = *(const bf16x8*)&As[wr * 64 + mi * 16 + l15][g * 8];   \
        _Pragma("unroll")                                                   \
        for (int ni = 0; ni < 4; ++ni)                                      \
            bb[ni] = *(const bf16x8*)&Bs[wc * 64 + ni * 16 + l15][g * 8];   \
        __builtin_amdgcn_s_setprio(1);                                      \
        _Pragma("unroll")                                                   \
        for (int mi = 0; mi < 4; ++mi)                                      \
            _Pragma("unroll")                                               \
            for (int ni = 0; ni < 4; ++ni)                                  \
                acc[mi][ni] = __builtin_amdgcn_mfma_f32_16x16x32_bf16(      \
                    af[mi], bb[ni], acc[mi][ni], 0, 0, 0);                  \
        __builtin_amdgcn_s_setprio(0);                                      \
    }                                                                       \
} while (0)

#define KLOOP(NT_) do {                                                     \
    for (int t = 0; t < (NT_); ++t) {                                       \
        STAGE8(t * 64);                                                     \
        asm volatile("s_waitcnt vmcnt(0)" ::: "memory");                    \
        __syncthreads();                                                    \
        TILE_BODY();                                                        \
        __syncthreads();                                                    \
    }                                                                       \
} while (0)

// ---------------- kernel B: gemm1 U conv_w2 ----------------
// blocks [0,2048): gemm1 (R8-verbatim); blocks [2048,10240): conv_w2 tile
// (K=FFN -> 64 kb, N=HS -> 16 nb) into DISJOINT w2t region.
__global__ __launch_bounds__(256) void gemm1_kernel(const __bf16* __restrict__ xb,
                                                    const __bf16* __restrict__ w1t,
                                                    const int* __restrict__ perm,
                                                    __bf16* __restrict__ hbuf,
                                                    const float* __restrict__ w2,
                                                    __bf16* __restrict__ w2t,
                                                    int fused) {
    __shared__ __bf16 As[128][64];
    __shared__ __bf16 Bs[128][64];
    const int tid = threadIdx.x;

    if (blockIdx.x >= 2048) {
        if (fused) {
            // ---- conv_w2 tile (verbatim conv_wt body, K=FFN, N=HS) ----
            __bf16 (*t)[72] = (__bf16(*)[72])(&As[0][0]);
            const int cb = blockIdx.x - 2048;
            const int e = cb >> 10, r = cb & 1023;
            const int kb = (r >> 4) * 64, nb = (r & 15) * 64;
            const float* src = w2 + ((size_t)e * FFN + kb) * HS + nb;
            {
                const int kk = tid >> 4, nc = (tid & 15) * 4;
#pragma unroll
                for (int i = 0; i < 4; ++i) {
                    int k = kk + 16 * i;
                    f4 v = *(const f4*)(src + (size_t)k * HS + nc);
                    t[nc + 0][k] = (__bf16)v[0];
                    t[nc + 1][k] = (__bf16)v[1];
                    t[nc + 2][k] = (__bf16)v[2];
                    t[nc + 3][k] = (__bf16)v[3];
                }
            }
            __syncthreads();
            __bf16* dst = w2t + ((size_t)e * HS + nb) * FFN + kb;
            const int nn = tid >> 3, ch = (tid & 7) * 8;
#pragma unroll
            for (int i = 0; i < 2; ++i) {
                int n = nn + 32 * i;
                bf16x8 v = *(const bf16x8*)(&t[n][ch]);
                *(bf16x8*)(dst + (size_t)n * FFN + ch) = v;
            }
        }
        return;
    }

    // ---- gemm1 (R8-verbatim) ----
    const int hw = blockIdx.x;
    const int logical = (hw & 7) * 256 + (hw >> 3);   // bijective, nwg=2048
    const int nblk = logical & 31;
    const int mblk = (logical >> 5) & 7;
    const int e    = logical >> 8;
    const int lane = tid & 63, w = tid >> 6;  // w in 0..3
    const int wr = w >> 1, wc = w & 1;
    const int l15 = lane & 15;
    const int srl = lane >> 3;
    const int gsrc = (lane & 7) ^ srl;

    const __bf16* aptr[4];
    const __bf16* bptr[4];
#pragma unroll
    for (int j = 0; j < 4; ++j) {
        int arow = j * 32 + w * 8 + srl;
        int p = perm[e * CAP + mblk * 128 + arow];
        int tok = (p < 0) ? 0 : (p >> 1);
        aptr[j] = xb + (size_t)tok * HS + gsrc * 8;
        int brow = nblk * 128 + j * 32 + w * 8 + srl;
        bptr[j] = w1t + ((size_t)e * FFN + brow) * HS + gsrc * 8;
    }

    f32x4 acc[4][4];
#pragma unroll
    for (int mi = 0; mi < 4; ++mi)
#pragma unroll
        for (int ni = 0; ni < 4; ++ni) acc[mi][ni] = (f32x4)0.0f;

    KLOOP(HS / 64);  // 16 K-tiles

    const int mbase = mblk * 128 + wr * 64;
    const int nbase = nblk * 128 + wc * 64;
#pragma unroll
    for (int mi = 0; mi < 4; ++mi) {
#pragma unroll
        for (int ni = 0; ni < 4; ++ni) {
#pragma unroll
            for (int reg = 0; reg < 4; ++reg) {
                int mrow = mbase + mi * 16 + (lane >> 4) * 4 + reg;
                int ncol = nbase + ni * 16 + l15;
                float z = acc[mi][ni][reg];
                // gelu(z) = 0.5 z (1+tanh(u)) == z * sigmoid(2u)
                float z2 = z * z;
                float y = z * (1.5957691216057308f + 0.07135481627f * z2);
                float ex = __expf(-y);
                float gv = z * __builtin_amdgcn_rcpf(1.0f + ex);
                hbuf[(size_t)(e * CAP + mrow) * FFN + ncol] = (__bf16)gv;
            }
        }
    }
}

// ---------------- GEMM2: K-split 2 -> 1024 blocks (4/CU) ----------------
__global__ __launch_bounds__(256) void gemm2_kernel(const __bf16* __restrict__ hbuf,
                                                    const __bf16* __restrict__ w2t,
                                                    const int* __restrict__ perm,
                                                    const float* __restrict__ ew,
                                                    float* __restrict__ out) {
    __shared__ __bf16 As[128][64];
    __shared__ __bf16 Bs[128][64];
    const int hw = blockIdx.x;
    const int logical = (hw & 7) * 128 + (hw >> 3);   // bijective, nwg=1024
    const int e    = logical >> 7;
    const int idx  = logical & 127;
    const int half = idx >> 6;
    const int mblk = (idx >> 3) & 7;
    const int nblk = idx & 7;
    const int tid = threadIdx.x, lane = tid & 63, w = tid >> 6;
    const int wr = w >> 1, wc = w & 1;
    const int l15 = lane & 15;
    const int srl = lane >> 3;
    const int gsrc = (lane & 7) ^ srl;
    const size_t kbase = (size_t)half * 2048;

    const __bf16* aptr[4];
    const __bf16* bptr[4];
#pragma unroll
    for (int j = 0; j < 4; ++j) {
        int arow = j * 32 + w * 8 + srl;
        aptr[j] = hbuf + ((size_t)(e * CAP + mblk * 128 + arow)) * FFN
                  + kbase + gsrc * 8;
        int brow = nblk * 128 + j * 32 + w * 8 + srl;
        bptr[j] = w2t + ((size_t)e * HS + brow) * FFN + kbase + gsrc * 8;
    }

    f32x4 acc[4][4];
#pragma unroll
    for (int mi = 0; mi < 4; ++mi)
#pragma unroll
        for (int ni = 0; ni < 4; ++ni) acc[mi][ni] = (f32x4)0.0f;

    KLOOP(2048 / 64);  // 32 K-tiles

    // reuse LDS for perm/weights of this block's 128 rows
    int* sperm = (int*)&As[0][0];
    float* swt = (float*)(sperm + 128);
    if (tid < 128) {
        int p = perm[e * CAP + mblk * 128 + tid];
        sperm[tid] = p;
        swt[tid] = (p >= 0) ? ew[p] : 0.0f;
    }
    __syncthreads();

    const int nbase = nblk * 128 + wc * 64;
#pragma unroll
    for (int mi = 0; mi < 4; ++mi) {
#pragma unroll
        for (int reg = 0; reg < 4; ++reg) {
            int mloc = wr * 64 + mi * 16 + (lane >> 4) * 4 + reg;
            int p = sperm[mloc];
            if (p >= 0) {
                int tok = p >> 1;
                float wgt = swt[mloc];
#pragma unroll
                for (int ni = 0; ni < 4; ++ni) {
                    int n = nbase + ni * 16 + l15;
                    atomicAdd(&out[(size_t)tok * HS + n], wgt * acc[mi][ni][reg]);
                }
            }
        }
    }
}

extern "C" void kernel_launch(void* const* d_in, const int* in_sizes, int n_in,
                              void* d_out, int out_size, void* d_ws, size_t ws_size,
                              hipStream_t stream) {
    const float* x    = (const float*)d_in[0];
    const float* rw   = (const float*)d_in[1];
    const float* w1   = (const float*)d_in[2];
    const float* w2   = (const float*)d_in[3];
    const float* bias = (const float*)d_in[4];
    float* out = (float*)d_out;
    char* ws = (char*)d_ws;

    __bf16* hbuf = (__bf16*)ws;
    int*    te   = (int*)(ws + WS_TE);
    float*  ew   = (float*)(ws + WS_EW);
    int*    perm = (int*)(ws + WS_PERM);
    __bf16* wt   = (__bf16*)(ws + WS_WT);
    __bf16* xb   = (__bf16*)(ws + WS_XB);
    __bf16* w2t  = (__bf16*)(ws + WS_W2T);

    const int fused = (ws_size >= (size_t)WS_W2T_END) ? 1 : 0;
    __bf16* w2dst = fused ? w2t : wt;

    hipLaunchKernelGGL(fused_pre_kernel, dim3(11264), dim3(256), 0, stream,
                       x, rw, te, ew, xb, w1, wt, out, bias);
    hipLaunchKernelGGL(sort_kernel, dim3(1), dim3(256), 0, stream, te, perm);
    hipLaunchKernelGGL(gemm1_kernel, dim3(fused ? 10240 : 2048), dim3(256), 0, stream,
                       xb, wt, perm, hbuf, w2, w2t, fused);
    if (!fused)
        hipLaunchKernelGGL(conv_wt_kernel, dim3(HS / 64, FFN / 64, NE), dim3(256),
                           0, stream, w2, wt, FFN, HS);
    hipLaunchKernelGGL(gemm2_kernel, dim3(1024), dim3(256), 0, stream,
                       hbuf, w2dst, perm, ew, out);
}